// Round 2
// baseline (187.741 us; speedup 1.0000x reference)
//
#include <hip/hip_runtime.h>

// Median blur 3x3, replicate borders, NHWC fp32 [B, 512, 512, 3].
// med9 = med3( max3(row mins), med3(row meds), min3(row maxes) )
// R1: 4-wide vectorized. Each thread owns 4 consecutive floats of a row and
// issues 3 aligned dwordx4 loads per row-step (left/mid/right blocks); the
// shifted l/m/r windows are extracted via register component selects.
// Replicate borders for the first/last group are synthesized from the mid
// vector's components (channel-aware), so no OOB loads and no scalar path.

#define IMG_H 512
#define IMG_W 512
#define IMG_C 3
#define ROW_F (IMG_W * IMG_C)   // 1536 floats per row
#define NGROUPS (ROW_F / 4)     // 384 float4-groups per row
#define TILE_H 8                // rows per thread (vertical rolling window)

__device__ __forceinline__ float med3f(float a, float b, float c) {
    return __builtin_amdgcn_fmed3f(a, b, c);
}
__device__ __forceinline__ float min3f(float a, float b, float c) {
    return fminf(fminf(a, b), c);
}
__device__ __forceinline__ float max3f(float a, float b, float c) {
    return fmaxf(fmaxf(a, b), c);
}

__device__ __forceinline__ float4 min3v(float4 a, float4 b, float4 c) {
    return make_float4(min3f(a.x,b.x,c.x), min3f(a.y,b.y,c.y),
                       min3f(a.z,b.z,c.z), min3f(a.w,b.w,c.w));
}
__device__ __forceinline__ float4 med3v(float4 a, float4 b, float4 c) {
    return make_float4(med3f(a.x,b.x,c.x), med3f(a.y,b.y,c.y),
                       med3f(a.z,b.z,c.z), med3f(a.w,b.w,c.w));
}
__device__ __forceinline__ float4 max3v(float4 a, float4 b, float4 c) {
    return make_float4(max3f(a.x,b.x,c.x), max3f(a.y,b.y,c.y),
                       max3f(a.z,b.z,c.z), max3f(a.w,b.w,c.w));
}

__global__ __launch_bounds__(128) void median3x3_kernel(
        const float* __restrict__ in, float* __restrict__ out) {
    const int g  = blockIdx.x * blockDim.x + threadIdx.x;   // 0..383
    const int b  = blockIdx.z;
    const int h0 = blockIdx.y * TILE_H;

    const bool left_edge  = (g == 0);
    const bool right_edge = (g == NGROUPS - 1);

    const float* base  = in  + (size_t)b * IMG_H * ROW_F + (size_t)g * 4;
    float*       obase = out + (size_t)b * IMG_H * ROW_F + (size_t)g * 4;

    float4 mn0, md0, mx0, mn1, md1, mx1, mn2, md2, mx2;

    auto loadrow = [&](int r, float4& mn, float4& md, float4& mx) {
        const float* p = base + (size_t)r * ROW_F;
        const float4 mb = *(const float4*)p;
        float4 l, rr;
        if (!left_edge) {
            const float4 lb = *(const float4*)(p - 4);
            l = make_float4(lb.y, lb.z, lb.w, mb.x);
        } else {
            // floats 0..3: w = 0,0,0,1 -> left = replicate(0..2), 0
            l = make_float4(mb.x, mb.y, mb.z, mb.x);
        }
        if (!right_edge) {
            const float4 rb = *(const float4*)(p + 4);
            rr = make_float4(mb.w, rb.x, rb.y, rb.z);
        } else {
            // floats 1532..1535: w = 510,511,511,511 -> right = 1535, replicate
            rr = make_float4(mb.w, mb.y, mb.z, mb.w);
        }
        mn = min3v(l, mb, rr);
        md = med3v(l, mb, rr);
        mx = max3v(l, mb, rr);
    };

    loadrow((h0 == 0) ? 0 : h0 - 1, mn0, md0, mx0);
    loadrow(h0, mn1, md1, mx1);

    #pragma unroll
    for (int i = 0; i < TILE_H; ++i) {
        const int h  = h0 + i;
        const int hp = (h == IMG_H - 1) ? h : h + 1;   // replicate bottom edge
        loadrow(hp, mn2, md2, mx2);

        const float4 A  = max3v(mn0, mn1, mn2);
        const float4 Bm = med3v(md0, md1, md2);
        const float4 Cm = min3v(mx0, mx1, mx2);
        *(float4*)(obase + (size_t)h * ROW_F) = med3v(A, Bm, Cm);

        mn0 = mn1; md0 = md1; mx0 = mx1;
        mn1 = mn2; md1 = md2; mx1 = mx2;
    }
}

extern "C" void kernel_launch(void* const* d_in, const int* in_sizes, int n_in,
                              void* d_out, int out_size, void* d_ws, size_t ws_size,
                              hipStream_t stream) {
    const float* in = (const float*)d_in[0];
    float* out = (float*)d_out;

    const int B = in_sizes[0] / (IMG_H * ROW_F);   // 32

    dim3 grid(NGROUPS / 128, IMG_H / TILE_H, B);   // (3, 64, 32)
    dim3 block(128, 1, 1);
    median3x3_kernel<<<grid, block, 0, stream>>>(in, out);
}